// Round 6
// baseline (170.142 us; speedup 1.0000x reference)
//
#include <hip/hip_runtime.h>
#include <stdint.h>

// Problem constants (B=8, Sq=Sk=1024, D=U=512, H=8, Dh=64)
#define ROWS 8192            // B*Sq = B*Sk
#define UDIM 512
#define SEQ  1024
#define NH   8
#define DH   64
#define SCALE 0.125f         // 1/sqrt(64)
#define LOG2E 1.44269504f
#define SC_Q (SCALE * LOG2E) // folded into Q projection epilogue

typedef unsigned short u16;
typedef __bf16 bf16_t;
typedef bf16_t bf16x8 __attribute__((ext_vector_type(8)));
typedef float f32x4 __attribute__((ext_vector_type(4)));

__device__ __forceinline__ u16 f2bf(float f) {
    union { float f; uint32_t u; } v; v.f = f;
    uint32_t r = v.u + 0x7FFFu + ((v.u >> 16) & 1u);   // round-to-nearest-even
    return (u16)(r >> 16);
}

__device__ __forceinline__ uint32_t pk_bf16(float a, float b) {
#if __has_builtin(__builtin_amdgcn_cvt_pk_bf16_f32)
    typedef __bf16 bf16x2_t __attribute__((ext_vector_type(2)));
    bf16x2_t r = __builtin_amdgcn_cvt_pk_bf16_f32(a, b);
    union { bf16x2_t v; uint32_t u; } c; c.v = r;
    return c.u;
#else
    return (uint32_t)f2bf(a) | ((uint32_t)f2bf(b) << 16);
#endif
}

__device__ __forceinline__ void async_ld16(u16* lds, const u16* g) {
    __builtin_amdgcn_global_load_lds((const __attribute__((address_space(1))) void*)g,
                                     (__attribute__((address_space(3))) void*)lds, 16, 0, 0);
}

// ---------------------------------------------------------------------------
// queries/keys -> bf16 (y selects src); one wave per row
__global__ void convqk_kernel(const float* __restrict__ q, const float* __restrict__ k,
                              u16* __restrict__ qb, u16* __restrict__ kb) {
    int w = threadIdx.x >> 6, lane = threadIdx.x & 63;
    int row = blockIdx.x * 4 + w;
    const float* src = (blockIdx.y == 0) ? q : k;
    u16* dst = (blockIdx.y == 0) ? qb : kb;
    const float4* s4 = (const float4*)(src + (size_t)row * UDIM);
    ushort4* o4 = (ushort4*)(dst + (size_t)row * UDIM);
    for (int j = 0; j < 2; j++) {
        float4 v = s4[j * 64 + lane];
        ushort4 b;
        b.x = f2bf(v.x); b.y = f2bf(v.y); b.z = f2bf(v.z); b.w = f2bf(v.w);
        o4[j * 64 + lane] = b;
    }
}

// W[k][n] (512x512 f32) -> Wt[n][k] bf16, tiled via LDS. blockIdx.z selects q/k/v.
__global__ void transposeW_kernel(const float* __restrict__ Wq, const float* __restrict__ Wk,
                                  const float* __restrict__ Wv, u16* __restrict__ Wqt,
                                  u16* __restrict__ Wkt, u16* __restrict__ Wvt) {
    const float* in = (blockIdx.z == 0) ? Wq : (blockIdx.z == 1) ? Wk : Wv;
    u16* out = (blockIdx.z == 0) ? Wqt : (blockIdx.z == 1) ? Wkt : Wvt;
    __shared__ float tile[32][33];
    int k0 = blockIdx.y * 32, n0 = blockIdx.x * 32;
    int tx = threadIdx.x & 31, ty = threadIdx.x >> 5;
    for (int r = ty; r < 32; r += 8)
        tile[r][tx] = in[(size_t)(k0 + r) * UDIM + n0 + tx];
    __syncthreads();
    for (int r = ty; r < 32; r += 8)
        out[(size_t)(n0 + r) * UDIM + k0 + tx] = f2bf(tile[tx][r]);
}

// ---------------------------------------------------------------------------
// Fused QKV projection, 128x128 tile, XOR-swizzled staging LDS, pointer-
// incremented global_load_lds, LDS-staged coalesced epilogue (dwordx4 stores).
// z==0 (Q): epilogue multiplies by SCALE*LOG2E. z==2 (V): Vt[b][u][sk].
#define CPAD 136   // c_s row stride in u16
__global__ __launch_bounds__(256, 3) void proj_kernel(
    const u16* __restrict__ qb, const u16* __restrict__ kb,
    const u16* __restrict__ Wqt, const u16* __restrict__ Wkt, const u16* __restrict__ Wvt,
    const float* __restrict__ bq, const float* __restrict__ bk, const float* __restrict__ bv,
    u16* __restrict__ Qp, u16* __restrict__ Kp, u16* __restrict__ Vtp)
{
    const int z = blockIdx.z;
    const u16* A = (z == 0) ? qb : kb;
    const u16* W = (z == 0) ? Wqt : (z == 1) ? Wkt : Wvt;
    const float* bias = (z == 0) ? bq : (z == 1) ? bk : bv;

    __shared__ u16 smem[128 * CPAD];
    u16* a_s = smem;
    u16* b_s = smem + 4096;
    u16* c_s = smem;

    const int t = threadIdx.x;
    const int lane = t & 63, w = t >> 6;
    const int quad = lane >> 4, l15 = lane & 15;
    const int m0 = blockIdx.x * 128;
    const int n0 = blockIdx.y * 128;

    const int r0 = t >> 2;
    const int s0 = ((t & 3) ^ ((r0 >> 1) & 3)) * 8;
    const u16* Ag0 = &A[(size_t)(m0 + r0) * 512 + s0];
    const u16* Ag1 = Ag0 + (size_t)64 * 512;
    const u16* Wg0 = &W[(size_t)(n0 + r0) * 512 + s0];
    const u16* Wg1 = Wg0 + (size_t)64 * 512;
    u16* al0 = &a_s[t * 8];       u16* al1 = &a_s[(t + 256) * 8];
    u16* bl0 = &b_s[t * 8];       u16* bl1 = &b_s[(t + 256) * 8];

    int aoff[2], boff[8];
    for (int mi = 0; mi < 2; mi++) {
        int row = w * 32 + mi * 16 + l15;
        aoff[mi] = row * 32 + (quad ^ ((row >> 1) & 3)) * 8;
    }
    for (int ni = 0; ni < 8; ni++) {
        int row = ni * 16 + l15;
        boff[ni] = row * 32 + (quad ^ ((row >> 1) & 3)) * 8;
    }

    f32x4 acc[2][8];
    for (int mi = 0; mi < 2; mi++)
        for (int ni = 0; ni < 8; ni++)
            acc[mi][ni] = (f32x4){0.f, 0.f, 0.f, 0.f};

    for (int kt = 0; kt < 512; kt += 32) {
        async_ld16(al0, Ag0);  async_ld16(al1, Ag1);
        async_ld16(bl0, Wg0);  async_ld16(bl1, Wg1);
        Ag0 += 32; Ag1 += 32; Wg0 += 32; Wg1 += 32;
        __syncthreads();
        bf16x8 af[2], bf[8];
        for (int mi = 0; mi < 2; mi++) af[mi] = *(const bf16x8*)&a_s[aoff[mi]];
        for (int ni = 0; ni < 8; ni++) bf[ni] = *(const bf16x8*)&b_s[boff[ni]];
        for (int mi = 0; mi < 2; mi++)
            for (int ni = 0; ni < 8; ni++)
                acc[mi][ni] = __builtin_amdgcn_mfma_f32_16x16x32_bf16(af[mi], bf[ni], acc[mi][ni], 0, 0, 0);
        __syncthreads();
    }

    const float qscale = (z == 0) ? SC_Q : 1.f;
    float bvl[8];
    for (int ni = 0; ni < 8; ni++) bvl[ni] = bias[n0 + ni * 16 + l15];
    for (int mi = 0; mi < 2; mi++)
        for (int ni = 0; ni < 8; ni++)
            for (int r = 0; r < 4; r++)
                acc[mi][ni][r] = fmaxf(acc[mi][ni][r] + bvl[ni], 0.f) * qscale;

    if (z < 2) {
        for (int mi = 0; mi < 2; mi++)
            for (int ni = 0; ni < 8; ni++)
                for (int r = 0; r < 4; r++)
                    c_s[(w * 32 + mi * 16 + quad * 4 + r) * CPAD + ni * 16 + l15] =
                        f2bf(acc[mi][ni][r]);
        __syncthreads();
        u16* outp = (z == 0) ? Qp : Kp;
        for (int j = 0; j < 8; j++) {
            int c = t + j * 256;
            int mrow = c >> 4, col8 = c & 15;
            uint4 d = *(const uint4*)&c_s[mrow * CPAD + col8 * 8];
            *(uint4*)&outp[(size_t)(m0 + mrow) * 512 + n0 + col8 * 8] = d;
        }
    } else {
        for (int mi = 0; mi < 2; mi++)
            for (int ni = 0; ni < 8; ni++) {
                uint2 pk;
                pk.x = pk_bf16(acc[mi][ni][0], acc[mi][ni][1]);
                pk.y = pk_bf16(acc[mi][ni][2], acc[mi][ni][3]);
                *(uint2*)&c_s[(ni * 16 + l15) * CPAD + w * 32 + mi * 16 + quad * 4] = pk;
            }
        __syncthreads();
        const int bb = m0 >> 10, sk0 = m0 & 1023;
        for (int j = 0; j < 8; j++) {
            int c = t + j * 256;
            int nrow = c >> 4, col8 = c & 15;
            uint4 d = *(const uint4*)&c_s[nrow * CPAD + col8 * 8];
            *(uint4*)&Vtp[(size_t)(bb * 512 + n0 + nrow) * 1024 + sk0 + col8 * 8] = d;
        }
    }
}

// ---------------------------------------------------------------------------
// Flash attention, BQ=128 q-rows per block (2 q-subtiles of 64 per wave-group).
// Transposed-score formulation, no online max (scores >= 0, scale folded in Q).
// Two-phase kv-iter with a barrier BETWEEN the P writes and P reads:
//   stage K/V -> barrier A -> read K/V frags + QK^T + exp2 + write P (both
//   subtiles) -> barrier B -> PV MFMAs (read p_s + register V frags only).
// Barrier A orders iter-i+1 P-writes after iter-i P-reads; barrier B orders
// P-writes before P-reads and frees k_s/v_s for restaging. 2 barriers/iter.
__global__ __launch_bounds__(256, 3) void attn_kernel(
    const u16* __restrict__ Qb, const u16* __restrict__ Kb, const u16* __restrict__ Vt,
    float* __restrict__ O)
{
    __shared__ u16 q_s[128 * 64];  // [q][d]   swizzled (16 KB)
    __shared__ u16 k_s[64 * 64];   // [kv][d]  swizzled (8 KB)
    __shared__ u16 v_s[64 * 64];   // [d][kv]  swizzled (8 KB)
    __shared__ u16 p_s[128 * 64];  // [q][kv]  swizzled (16 KB)

    const int t = threadIdx.x, lane = t & 63, w = t >> 6;
    const int quad = lane >> 4, l15 = lane & 15;
    const int fid = blockIdx.x;         // 0..511
    const int xcd = fid & 7, j = fid >> 3;
    const int hb = xcd * 8 + (j & 7);   // 8 (b,h) groups per XCD
    const int qt = j >> 3;              // 0..7
    const int h = hb & 7, b = hb >> 3;
    const int q0 = qt * 128;

    // ---- hoisted staging addresses ----
    const int r0 = t >> 3;                              // 0..31
    const int s0 = ((t & 7) ^ (r0 & 7)) * 8;            // u16 offset
    u16* kl0 = &k_s[t * 8];       u16* kl1 = &k_s[(t + 256) * 8];
    u16* vl0 = &v_s[t * 8];       u16* vl1 = &v_s[(t + 256) * 8];
    const u16* kg0 = &Kb[(size_t)(b * 1024 + r0) * 512 + h * 64 + s0];
    const u16* kg1 = kg0 + (size_t)32 * 512;
    const u16* vg0 = &Vt[(size_t)(b * 512 + h * 64 + r0) * 1024 + s0];
    const u16* vg1 = vg0 + (size_t)32 * 1024;

    // stage Q tile (16 KB, 1024 chunks, 4 per thread)
    for (int rnd = 0; rnd < 4; rnd++) {
        int c = t + rnd * 256;
        int row = c >> 3;
        int jg = (c & 7) ^ (row & 7);
        async_ld16(&q_s[c * 8], &Qb[(size_t)(b * 1024 + q0 + row) * 512 + h * 64 + jg * 8]);
    }
    __syncthreads();

    // preload Q B-fragments for both subtiles: q row = s*64 + w*16 + l15
    const int prow0 = w * 16 + l15;
    bf16x8 bqf[2][2];
    for (int s = 0; s < 2; s++) {
        int row = s * 64 + prow0;
        for (int kk = 0; kk < 2; kk++)
            bqf[s][kk] = *(const bf16x8*)&q_s[row * 64 + ((kk * 4 + quad) ^ (row & 7)) * 8];
    }

    // ---- hoisted LDS fragment offsets ----
    int koff[4][2], pwoff[2][4], proff[2][2];
    for (int mi = 0; mi < 4; mi++) {
        int row = mi * 16 + l15;
        koff[mi][0] = row * 64 + (quad ^ (row & 7)) * 8;
        koff[mi][1] = row * 64 + ((4 + quad) ^ (row & 7)) * 8;
    }
    for (int s = 0; s < 2; s++) {
        int row = s * 64 + prow0;
        for (int mi = 0; mi < 4; mi++)
            pwoff[s][mi] = row * 64 + ((mi * 2 + (quad >> 1)) ^ (row & 7)) * 8 + (quad & 1) * 4;
        for (int kk = 0; kk < 2; kk++)
            proff[s][kk] = row * 64 + ((kk * 4 + quad) ^ (row & 7)) * 8;
    }

    float l_lane[2] = {0.f, 0.f};
    f32x4 o_acc[2][4];
    for (int s = 0; s < 2; s++)
        for (int mi = 0; mi < 4; mi++) o_acc[s][mi] = (f32x4){0.f, 0.f, 0.f, 0.f};

    for (int it = 0; it < 16; it++) {
        async_ld16(kl0, kg0);  async_ld16(kl1, kg1);
        async_ld16(vl0, vg0);  async_ld16(vl1, vg1);
        kg0 += (size_t)64 * 512; kg1 += (size_t)64 * 512;
        vg0 += 64; vg1 += 64;
        __syncthreads();   // barrier A: staging landed; prev-iter p_s reads done

        // K and V fragments once, reused by both q-subtiles
        bf16x8 ak[4][2];
        for (int mi = 0; mi < 4; mi++) {
            ak[mi][0] = *(const bf16x8*)&k_s[koff[mi][0]];
            ak[mi][1] = *(const bf16x8*)&k_s[koff[mi][1]];
        }
        bf16x8 av[2][4];
        for (int kk = 0; kk < 2; kk++)
            for (int mi = 0; mi < 4; mi++)
                av[kk][mi] = *(const bf16x8*)&v_s[koff[mi][kk]];   // same row formula (d rows)

        // phase 1: S^T = K·Q^T (log2-scaled via Q), exp2, pack, P -> p_s
        for (int s = 0; s < 2; s++) {
            f32x4 st[4];
            for (int mi = 0; mi < 4; mi++) {
                f32x4 a = (f32x4){0.f, 0.f, 0.f, 0.f};
                a = __builtin_amdgcn_mfma_f32_16x16x32_bf16(ak[mi][0], bqf[s][0], a, 0, 0, 0);
                a = __builtin_amdgcn_mfma_f32_16x16x32_bf16(ak[mi][1], bqf[s][1], a, 0, 0, 0);
                st[mi] = a;
            }
            for (int mi = 0; mi < 4; mi++) {
                float p0 = exp2f(st[mi][0]);
                float p1 = exp2f(st[mi][1]);
                float p2 = exp2f(st[mi][2]);
                float p3 = exp2f(st[mi][3]);
                l_lane[s] += (p0 + p1) + (p2 + p3);
                uint2 pk;
                pk.x = pk_bf16(p0, p1);
                pk.y = pk_bf16(p2, p3);
                *(uint2*)&p_s[pwoff[s][mi]] = pk;
            }
        }
        __syncthreads();   // barrier B: P visible; k_s/v_s free for restage

        // phase 2: O^T += V^T · P (reads p_s + registers only)
        for (int s = 0; s < 2; s++)
            for (int kk = 0; kk < 2; kk++) {
                bf16x8 bp = *(const bf16x8*)&p_s[proff[s][kk]];
                for (int mi = 0; mi < 4; mi++)
                    o_acc[s][mi] = __builtin_amdgcn_mfma_f32_16x16x32_bf16(av[kk][mi], bp, o_acc[s][mi], 0, 0, 0);
            }
    }

    for (int s = 0; s < 2; s++) {
        float l = l_lane[s];
        l += __shfl_xor(l, 16, 64);
        l += __shfl_xor(l, 32, 64);
        float inv = 1.f / l;
        int gq = q0 + s * 64 + prow0;
        for (int mi = 0; mi < 4; mi++) {
            float4 o;
            o.x = o_acc[s][mi][0] * inv;
            o.y = o_acc[s][mi][1] * inv;
            o.z = o_acc[s][mi][2] * inv;
            o.w = o_acc[s][mi][3] * inv;
            *(float4*)&O[(size_t)(b * 1024 + gq) * 512 + h * 64 + mi * 16 + quad * 4] = o;
        }
    }
}

// ---------------------------------------------------------------------------
// LayerNorm epilogue with inline qmask: mask = (sum|q_row| > 0);
// x = O*mask + q; LN over U=512; one wave per row.
__global__ void ln_kernel(const float* __restrict__ O, const float* __restrict__ q,
                          const float* __restrict__ gamma, const float* __restrict__ beta,
                          float* __restrict__ out)
{
    int w = threadIdx.x >> 6, lane = threadIdx.x & 63;
    int row = blockIdx.x * 4 + w;
    const float4* O4 = (const float4*)(O + (size_t)row * UDIM);
    const float4* q4 = (const float4*)(q + (size_t)row * UDIM);
    float4* o4 = (float4*)(out + (size_t)row * UDIM);

    float4 qq[2], oo[2];
    float am = 0.f;
    for (int j = 0; j < 2; j++) {
        qq[j] = q4[j * 64 + lane];
        oo[j] = O4[j * 64 + lane];
        am += fabsf(qq[j].x) + fabsf(qq[j].y) + fabsf(qq[j].z) + fabsf(qq[j].w);
    }
    for (int off = 32; off; off >>= 1) am += __shfl_xor(am, off, 64);
    float mask = (am > 0.f) ? 1.f : 0.f;

    float4 x[2];
    float s = 0.f, ss = 0.f;
    for (int j = 0; j < 2; j++) {
        float4 v;
        v.x = oo[j].x * mask + qq[j].x;
        v.y = oo[j].y * mask + qq[j].y;
        v.z = oo[j].z * mask + qq[j].z;
        v.w = oo[j].w * mask + qq[j].w;
        x[j] = v;
        s += v.x + v.y + v.z + v.w;
        ss += v.x * v.x + v.y * v.y + v.z * v.z + v.w * v.w;
    }
    for (int off = 32; off; off >>= 1) {
        s += __shfl_xor(s, off, 64);
        ss += __shfl_xor(ss, off, 64);
    }
    float mu = s * (1.f / 512.f);
    float var = ss * (1.f / 512.f) - mu * mu;
    float rs = rsqrtf(var + 1e-8f);
    for (int j = 0; j < 2; j++) {
        float4 g = ((const float4*)gamma)[j * 64 + lane];
        float4 bb = ((const float4*)beta)[j * 64 + lane];
        float4 v;
        v.x = g.x * (x[j].x - mu) * rs + bb.x;
        v.y = g.y * (x[j].y - mu) * rs + bb.y;
        v.z = g.z * (x[j].z - mu) * rs + bb.z;
        v.w = g.w * (x[j].w - mu) * rs + bb.w;
        o4[j * 64 + lane] = v;
    }
}

// ---------------------------------------------------------------------------
extern "C" void kernel_launch(void* const* d_in, const int* in_sizes, int n_in,
                              void* d_out, int out_size, void* d_ws, size_t ws_size,
                              hipStream_t stream)
{
    const float* queries = (const float*)d_in[0];
    const float* keys    = (const float*)d_in[1];
    const float* Wq      = (const float*)d_in[2];
    const float* bq      = (const float*)d_in[3];
    const float* Wk      = (const float*)d_in[4];
    const float* bk      = (const float*)d_in[5];
    const float* Wv      = (const float*)d_in[6];
    const float* bv      = (const float*)d_in[7];
    const float* gamma   = (const float*)d_in[8];
    const float* beta    = (const float*)d_in[9];
    float* out = (float*)d_out;

    char* ws = (char*)d_ws;
    size_t off = 0;
    auto alloc = [&](size_t bytes) {
        void* p = ws + off;
        off += (bytes + 255) & ~(size_t)255;
        return p;
    };
    u16* qb   = (u16*)alloc((size_t)ROWS * UDIM * 2);
    u16* kb   = (u16*)alloc((size_t)ROWS * UDIM * 2);
    u16* Wqt  = (u16*)alloc((size_t)UDIM * UDIM * 2);
    u16* Wkt  = (u16*)alloc((size_t)UDIM * UDIM * 2);
    u16* Wvt  = (u16*)alloc((size_t)UDIM * UDIM * 2);
    u16* Qp   = (u16*)alloc((size_t)ROWS * UDIM * 2);
    u16* Kp   = (u16*)alloc((size_t)ROWS * UDIM * 2);
    u16* Vtp  = (u16*)alloc((size_t)ROWS * UDIM * 2);
    float* Of = (float*)alloc((size_t)ROWS * UDIM * 4);

    convqk_kernel<<<dim3(ROWS / 4, 2), 256, 0, stream>>>(queries, keys, qb, kb);
    transposeW_kernel<<<dim3(16, 16, 3), 256, 0, stream>>>(Wq, Wk, Wv, Wqt, Wkt, Wvt);
    proj_kernel<<<dim3(64, 4, 3), 256, 0, stream>>>(qb, kb, Wqt, Wkt, Wvt, bq, bk, bv, Qp, Kp, Vtp);
    attn_kernel<<<512, 256, 0, stream>>>(Qp, Kp, Vtp, Of);
    ln_kernel<<<ROWS / 4, 256, 0, stream>>>(Of, queries, gamma, beta, out);
}

// Round 8
// 162.427 us; speedup vs baseline: 1.0475x; 1.0475x over previous
//
#include <hip/hip_runtime.h>
#include <stdint.h>

// Problem constants (B=8, Sq=Sk=1024, D=U=512, H=8, Dh=64)
#define ROWS 8192            // B*Sq = B*Sk
#define UDIM 512
#define SEQ  1024
#define NH   8
#define DH   64
#define SCALE 0.125f         // 1/sqrt(64)
#define LOG2E 1.44269504f
#define SC_Q (SCALE * LOG2E) // folded into Q projection epilogue

typedef unsigned short u16;
typedef __bf16 bf16_t;
typedef bf16_t bf16x8 __attribute__((ext_vector_type(8)));
typedef float f32x4 __attribute__((ext_vector_type(4)));

__device__ __forceinline__ u16 f2bf(float f) {
    union { float f; uint32_t u; } v; v.f = f;
    uint32_t r = v.u + 0x7FFFu + ((v.u >> 16) & 1u);   // round-to-nearest-even
    return (u16)(r >> 16);
}

__device__ __forceinline__ uint32_t pk_bf16(float a, float b) {
#if __has_builtin(__builtin_amdgcn_cvt_pk_bf16_f32)
    typedef __bf16 bf16x2_t __attribute__((ext_vector_type(2)));
    bf16x2_t r = __builtin_amdgcn_cvt_pk_bf16_f32(a, b);
    union { bf16x2_t v; uint32_t u; } c; c.v = r;
    return c.u;
#else
    return (uint32_t)f2bf(a) | ((uint32_t)f2bf(b) << 16);
#endif
}

__device__ __forceinline__ void async_ld16(u16* lds, const u16* g) {
    __builtin_amdgcn_global_load_lds((const __attribute__((address_space(1))) void*)g,
                                     (__attribute__((address_space(3))) void*)lds, 16, 0, 0);
}

// ---------------------------------------------------------------------------
// queries/keys -> bf16 (y selects src); one wave per row
__global__ void convqk_kernel(const float* __restrict__ q, const float* __restrict__ k,
                              u16* __restrict__ qb, u16* __restrict__ kb) {
    int w = threadIdx.x >> 6, lane = threadIdx.x & 63;
    int row = blockIdx.x * 4 + w;
    const float* src = (blockIdx.y == 0) ? q : k;
    u16* dst = (blockIdx.y == 0) ? qb : kb;
    const float4* s4 = (const float4*)(src + (size_t)row * UDIM);
    ushort4* o4 = (ushort4*)(dst + (size_t)row * UDIM);
    for (int j = 0; j < 2; j++) {
        float4 v = s4[j * 64 + lane];
        ushort4 b;
        b.x = f2bf(v.x); b.y = f2bf(v.y); b.z = f2bf(v.z); b.w = f2bf(v.w);
        o4[j * 64 + lane] = b;
    }
}

// W[k][n] (512x512 f32) -> Wt[n][k] bf16, tiled via LDS. blockIdx.z selects q/k/v.
__global__ void transposeW_kernel(const float* __restrict__ Wq, const float* __restrict__ Wk,
                                  const float* __restrict__ Wv, u16* __restrict__ Wqt,
                                  u16* __restrict__ Wkt, u16* __restrict__ Wvt) {
    const float* in = (blockIdx.z == 0) ? Wq : (blockIdx.z == 1) ? Wk : Wv;
    u16* out = (blockIdx.z == 0) ? Wqt : (blockIdx.z == 1) ? Wkt : Wvt;
    __shared__ float tile[32][33];
    int k0 = blockIdx.y * 32, n0 = blockIdx.x * 32;
    int tx = threadIdx.x & 31, ty = threadIdx.x >> 5;
    for (int r = ty; r < 32; r += 8)
        tile[r][tx] = in[(size_t)(k0 + r) * UDIM + n0 + tx];
    __syncthreads();
    for (int r = ty; r < 32; r += 8)
        out[(size_t)(n0 + r) * UDIM + k0 + tx] = f2bf(tile[tx][r]);
}

// ---------------------------------------------------------------------------
// Fused QKV projection, 128x128 tile, XOR-swizzled DOUBLE-BUFFERED staging,
// prefetch issued at TOP of each k-iter (flies under MFMA phase), ONE barrier
// per iter. All hazards barrier-ordered:
//   frag reads of buf[cur] < barrier(i) < prefetch-write of buf[cur] (iter i+1)
//   prefetch(i)->buf[nxt] drained at barrier(i) < frag reads (iter i+1)
// z==0 (Q): epilogue multiplies by SCALE*LOG2E. z==2 (V): Vt[b][u][sk].
#define CPAD 136   // c_s row stride in u16
__global__ __launch_bounds__(256, 3) void proj_kernel(
    const u16* __restrict__ qb, const u16* __restrict__ kb,
    const u16* __restrict__ Wqt, const u16* __restrict__ Wkt, const u16* __restrict__ Wvt,
    const float* __restrict__ bq, const float* __restrict__ bk, const float* __restrict__ bv,
    u16* __restrict__ Qp, u16* __restrict__ Kp, u16* __restrict__ Vtp)
{
    const int z = blockIdx.z;
    const u16* A = (z == 0) ? qb : kb;
    const u16* W = (z == 0) ? Wqt : (z == 1) ? Wkt : Wvt;
    const float* bias = (z == 0) ? bq : (z == 1) ? bk : bv;

    __shared__ u16 smem[128 * CPAD];    // 34816 B; staging uses first 32 KB
    // staging layout (u16 indices): a[0]=0, a[1]=4096, b[0]=8192, b[1]=12288
    u16* c_s = smem;                    // epilogue reuses everything

    const int t = threadIdx.x;
    const int lane = t & 63, w = t >> 6;
    const int quad = lane >> 4, l15 = lane & 15;
    const int m0 = blockIdx.x * 128;
    const int n0 = blockIdx.y * 128;

    const int r0 = t >> 2;
    const int s0 = ((t & 3) ^ ((r0 >> 1) & 3)) * 8;
    const u16* Ag0 = &A[(size_t)(m0 + r0) * 512 + s0];
    const u16* Ag1 = Ag0 + (size_t)64 * 512;
    const u16* Wg0 = &W[(size_t)(n0 + r0) * 512 + s0];
    const u16* Wg1 = Wg0 + (size_t)64 * 512;
    u16* al0[2] = { &smem[0 + t * 8],     &smem[4096 + t * 8] };
    u16* al1[2] = { &smem[0 + (t + 256) * 8], &smem[4096 + (t + 256) * 8] };
    u16* bl0[2] = { &smem[8192 + t * 8],      &smem[12288 + t * 8] };
    u16* bl1[2] = { &smem[8192 + (t + 256) * 8], &smem[12288 + (t + 256) * 8] };

    int aoff[2], boff[8];
    for (int mi = 0; mi < 2; mi++) {
        int row = w * 32 + mi * 16 + l15;
        aoff[mi] = row * 32 + (quad ^ ((row >> 1) & 3)) * 8;
    }
    for (int ni = 0; ni < 8; ni++) {
        int row = ni * 16 + l15;
        boff[ni] = row * 32 + (quad ^ ((row >> 1) & 3)) * 8;
    }

    f32x4 acc[2][8];
    for (int mi = 0; mi < 2; mi++)
        for (int ni = 0; ni < 8; ni++)
            acc[mi][ni] = (f32x4){0.f, 0.f, 0.f, 0.f};

    // prologue: stage k-tile 0 into buf 0
    async_ld16(al0[0], Ag0);  async_ld16(al1[0], Ag1);
    async_ld16(bl0[0], Wg0);  async_ld16(bl1[0], Wg1);
    Ag0 += 32; Ag1 += 32; Wg0 += 32; Wg1 += 32;
    __syncthreads();

    for (int kt = 0; kt < 16; kt++) {
        const int cur = kt & 1, nxt = cur ^ 1;
        if (kt < 15) {   // prefetch next k-tile; drained at this iter's barrier
            async_ld16(al0[nxt], Ag0);  async_ld16(al1[nxt], Ag1);
            async_ld16(bl0[nxt], Wg0);  async_ld16(bl1[nxt], Wg1);
            Ag0 += 32; Ag1 += 32; Wg0 += 32; Wg1 += 32;
        }
        const int ab = cur ? 4096 : 0, bb = cur ? 12288 : 8192;
        bf16x8 af[2], bf[8];
        for (int mi = 0; mi < 2; mi++) af[mi] = *(const bf16x8*)&smem[ab + aoff[mi]];
        for (int ni = 0; ni < 8; ni++) bf[ni] = *(const bf16x8*)&smem[bb + boff[ni]];
        for (int mi = 0; mi < 2; mi++)
            for (int ni = 0; ni < 8; ni++)
                acc[mi][ni] = __builtin_amdgcn_mfma_f32_16x16x32_bf16(af[mi], bf[ni], acc[mi][ni], 0, 0, 0);
        __syncthreads();   // drains prefetch; orders frag reads before refill
    }

    const float qscale = (z == 0) ? SC_Q : 1.f;
    float bvl[8];
    for (int ni = 0; ni < 8; ni++) bvl[ni] = bias[n0 + ni * 16 + l15];
    for (int mi = 0; mi < 2; mi++)
        for (int ni = 0; ni < 8; ni++)
            for (int r = 0; r < 4; r++)
                acc[mi][ni][r] = fmaxf(acc[mi][ni][r] + bvl[ni], 0.f) * qscale;

    if (z < 2) {
        for (int mi = 0; mi < 2; mi++)
            for (int ni = 0; ni < 8; ni++)
                for (int r = 0; r < 4; r++)
                    c_s[(w * 32 + mi * 16 + quad * 4 + r) * CPAD + ni * 16 + l15] =
                        f2bf(acc[mi][ni][r]);
        __syncthreads();
        u16* outp = (z == 0) ? Qp : Kp;
        for (int j = 0; j < 8; j++) {
            int c = t + j * 256;
            int mrow = c >> 4, col8 = c & 15;
            uint4 d = *(const uint4*)&c_s[mrow * CPAD + col8 * 8];
            *(uint4*)&outp[(size_t)(m0 + mrow) * 512 + n0 + col8 * 8] = d;
        }
    } else {
        for (int mi = 0; mi < 2; mi++)
            for (int ni = 0; ni < 8; ni++) {
                uint2 pk;
                pk.x = pk_bf16(acc[mi][ni][0], acc[mi][ni][1]);
                pk.y = pk_bf16(acc[mi][ni][2], acc[mi][ni][3]);
                *(uint2*)&c_s[(ni * 16 + l15) * CPAD + w * 32 + mi * 16 + quad * 4] = pk;
            }
        __syncthreads();
        const int bb2 = m0 >> 10, sk0 = m0 & 1023;
        for (int j = 0; j < 8; j++) {
            int c = t + j * 256;
            int nrow = c >> 4, col8 = c & 15;
            uint4 d = *(const uint4*)&c_s[nrow * CPAD + col8 * 8];
            *(uint4*)&Vtp[(size_t)(bb2 * 512 + n0 + nrow) * 1024 + sk0 + col8 * 8] = d;
        }
    }
}

// ---------------------------------------------------------------------------
// Flash attention, BQ=128, double-buffered K/V, TWO barriers per kv-iter
// (round-6 proven ordering) with the prefetch issued at the TOP of the iter
// so its latency is hidden under the whole QK^T+exp phase:
//   iter i: [prefetch->buf[nxt]] [phase1: frags from buf[cur], QK^T, exp,
//   P->p_s] [barrier B: P visible, prefetch drained, frag reads done]
//   [phase2: PV from p_s] [barrier A': p_s reads done before next writes]
// Ordering proof (all cross-wave hazards barrier-separated):
//   p_s: write(i) < B(i) < read(i) < A'(i) < write(i+1)
//   buf[cur(i)] reads < B(i) < prefetch-issue(i+1) into same buffer
//   prefetch(i)->buf[nxt] drained at B(i) < reads at iter i+1
__global__ __launch_bounds__(256, 2) void attn_kernel(
    const u16* __restrict__ Qb, const u16* __restrict__ Kb, const u16* __restrict__ Vt,
    float* __restrict__ O)
{
    __shared__ u16 k_s[2][64 * 64];   // [kv][d] swizzled, double-buffered (16 KB)
    __shared__ u16 v_s[2][64 * 64];   // [d][kv] swizzled, double-buffered (16 KB)
    __shared__ u16 p_s[128 * 64];     // [q][kv] swizzled (16 KB)

    const int t = threadIdx.x, lane = t & 63, w = t >> 6;
    const int quad = lane >> 4, l15 = lane & 15;
    const int fid = blockIdx.x;         // 0..511
    const int xcd = fid & 7, j = fid >> 3;
    const int hb = xcd * 8 + (j & 7);   // 8 (b,h) groups per XCD
    const int qt = j >> 3;              // 0..7
    const int h = hb & 7, b = hb >> 3;
    const int q0 = qt * 128;

    // ---- staging addresses (pointer-incremented) ----
    const int r0 = t >> 3;                              // 0..31
    const int s0 = ((t & 7) ^ (r0 & 7)) * 8;            // u16 offset
    const u16* kg0 = &Kb[(size_t)(b * 1024 + r0) * 512 + h * 64 + s0];
    const u16* kg1 = kg0 + (size_t)32 * 512;
    const u16* vg0 = &Vt[(size_t)(b * 512 + h * 64 + r0) * 1024 + s0];
    const u16* vg1 = vg0 + (size_t)32 * 1024;
    u16* kd0[2] = { &k_s[0][t * 8], &k_s[1][t * 8] };
    u16* kd1[2] = { &k_s[0][(t + 256) * 8], &k_s[1][(t + 256) * 8] };
    u16* vd0[2] = { &v_s[0][t * 8], &v_s[1][t * 8] };
    u16* vd1[2] = { &v_s[0][(t + 256) * 8], &v_s[1][(t + 256) * 8] };

    // ---- Q B-fragments straight from global (16B/lane contiguous) ----
    const int prow0 = w * 16 + l15;
    bf16x8 bqf[2][2];
    for (int s = 0; s < 2; s++) {
        int qrow = b * 1024 + q0 + s * 64 + prow0;
        for (int kk = 0; kk < 2; kk++)
            bqf[s][kk] = *(const bf16x8*)&Qb[(size_t)qrow * 512 + h * 64 + kk * 32 + quad * 8];
    }

    // ---- hoisted LDS fragment offsets ----
    int koff[4][2], pwoff[2][4], proff[2][2];
    for (int mi = 0; mi < 4; mi++) {
        int row = mi * 16 + l15;
        koff[mi][0] = row * 64 + (quad ^ (row & 7)) * 8;
        koff[mi][1] = row * 64 + ((4 + quad) ^ (row & 7)) * 8;
    }
    for (int s = 0; s < 2; s++) {
        int row = s * 64 + prow0;
        for (int mi = 0; mi < 4; mi++)
            pwoff[s][mi] = row * 64 + ((mi * 2 + (quad >> 1)) ^ (row & 7)) * 8 + (quad & 1) * 4;
        for (int kk = 0; kk < 2; kk++)
            proff[s][kk] = row * 64 + ((kk * 4 + quad) ^ (row & 7)) * 8;
    }

    float l_lane[2] = {0.f, 0.f};
    f32x4 o_acc[2][4];
    for (int s = 0; s < 2; s++)
        for (int mi = 0; mi < 4; mi++) o_acc[s][mi] = (f32x4){0.f, 0.f, 0.f, 0.f};

    // prologue: stage buf 0
    async_ld16(kd0[0], kg0);  async_ld16(kd1[0], kg1);
    async_ld16(vd0[0], vg0);  async_ld16(vd1[0], vg1);
    kg0 += (size_t)64 * 512; kg1 += (size_t)64 * 512;
    vg0 += 64; vg1 += 64;
    __syncthreads();

    for (int it = 0; it < 16; it++) {
        const int cur = it & 1, nxt = cur ^ 1;

        // prefetch next kv-tile (hidden under phase 1; drained at barrier B)
        if (it < 15) {
            async_ld16(kd0[nxt], kg0);  async_ld16(kd1[nxt], kg1);
            async_ld16(vd0[nxt], vg0);  async_ld16(vd1[nxt], vg1);
            kg0 += (size_t)64 * 512; kg1 += (size_t)64 * 512;
            vg0 += 64; vg1 += 64;
        }

        // phase 1: K/V fragment reads from cur buffer
        bf16x8 ak[4][2];
        for (int mi = 0; mi < 4; mi++) {
            ak[mi][0] = *(const bf16x8*)&k_s[cur][koff[mi][0]];
            ak[mi][1] = *(const bf16x8*)&k_s[cur][koff[mi][1]];
        }
        bf16x8 av[2][4];
        for (int kk = 0; kk < 2; kk++)
            for (int mi = 0; mi < 4; mi++)
                av[kk][mi] = *(const bf16x8*)&v_s[cur][koff[mi][kk]];  // same row formula (d rows)

        // S^T = K·Q^T (log2-scaled via Q), exp2, pack, P -> p_s
        for (int s = 0; s < 2; s++) {
            f32x4 st[4];
            for (int mi = 0; mi < 4; mi++) {
                f32x4 a = (f32x4){0.f, 0.f, 0.f, 0.f};
                a = __builtin_amdgcn_mfma_f32_16x16x32_bf16(ak[mi][0], bqf[s][0], a, 0, 0, 0);
                a = __builtin_amdgcn_mfma_f32_16x16x32_bf16(ak[mi][1], bqf[s][1], a, 0, 0, 0);
                st[mi] = a;
            }
            for (int mi = 0; mi < 4; mi++) {
                float p0 = exp2f(st[mi][0]);
                float p1 = exp2f(st[mi][1]);
                float p2 = exp2f(st[mi][2]);
                float p3 = exp2f(st[mi][3]);
                l_lane[s] += (p0 + p1) + (p2 + p3);
                uint2 pk;
                pk.x = pk_bf16(p0, p1);
                pk.y = pk_bf16(p2, p3);
                *(uint2*)&p_s[pwoff[s][mi]] = pk;
            }
        }

        __syncthreads();   // barrier B: P visible, prefetch drained, frag reads done

        // phase 2: O^T += V^T · P (reads p_s + registers only)
        for (int s = 0; s < 2; s++)
            for (int kk = 0; kk < 2; kk++) {
                bf16x8 bp = *(const bf16x8*)&p_s[proff[s][kk]];
                for (int mi = 0; mi < 4; mi++)
                    o_acc[s][mi] = __builtin_amdgcn_mfma_f32_16x16x32_bf16(av[kk][mi], bp, o_acc[s][mi], 0, 0, 0);
            }

        if (it < 15)
            __syncthreads();   // barrier A': p_s reads done before next iter's writes
    }

    for (int s = 0; s < 2; s++) {
        float l = l_lane[s];
        l += __shfl_xor(l, 16, 64);
        l += __shfl_xor(l, 32, 64);
        float inv = 1.f / l;
        int gq = q0 + s * 64 + prow0;
        for (int mi = 0; mi < 4; mi++) {
            float4 o;
            o.x = o_acc[s][mi][0] * inv;
            o.y = o_acc[s][mi][1] * inv;
            o.z = o_acc[s][mi][2] * inv;
            o.w = o_acc[s][mi][3] * inv;
            *(float4*)&O[(size_t)(b * 1024 + gq) * 512 + h * 64 + mi * 16 + quad * 4] = o;
        }
    }
}

// ---------------------------------------------------------------------------
// LayerNorm epilogue with inline qmask: mask = (sum|q_row| > 0);
// x = O*mask + q; LN over U=512; one wave per row.
__global__ void ln_kernel(const float* __restrict__ O, const float* __restrict__ q,
                          const float* __restrict__ gamma, const float* __restrict__ beta,
                          float* __restrict__ out)
{
    int w = threadIdx.x >> 6, lane = threadIdx.x & 63;
    int row = blockIdx.x * 4 + w;
    const float4* O4 = (const float4*)(O + (size_t)row * UDIM);
    const float4* q4 = (const float4*)(q + (size_t)row * UDIM);
    float4* o4 = (float4*)(out + (size_t)row * UDIM);

    float4 qq[2], oo[2];
    float am = 0.f;
    for (int j = 0; j < 2; j++) {
        qq[j] = q4[j * 64 + lane];
        oo[j] = O4[j * 64 + lane];
        am += fabsf(qq[j].x) + fabsf(qq[j].y) + fabsf(qq[j].z) + fabsf(qq[j].w);
    }
    for (int off = 32; off; off >>= 1) am += __shfl_xor(am, off, 64);
    float mask = (am > 0.f) ? 1.f : 0.f;

    float4 x[2];
    float s = 0.f, ss = 0.f;
    for (int j = 0; j < 2; j++) {
        float4 v;
        v.x = oo[j].x * mask + qq[j].x;
        v.y = oo[j].y * mask + qq[j].y;
        v.z = oo[j].z * mask + qq[j].z;
        v.w = oo[j].w * mask + qq[j].w;
        x[j] = v;
        s += v.x + v.y + v.z + v.w;
        ss += v.x * v.x + v.y * v.y + v.z * v.z + v.w * v.w;
    }
    for (int off = 32; off; off >>= 1) {
        s += __shfl_xor(s, off, 64);
        ss += __shfl_xor(ss, off, 64);
    }
    float mu = s * (1.f / 512.f);
    float var = ss * (1.f / 512.f) - mu * mu;
    float rs = rsqrtf(var + 1e-8f);
    for (int j = 0; j < 2; j++) {
        float4 g = ((const float4*)gamma)[j * 64 + lane];
        float4 bb = ((const float4*)beta)[j * 64 + lane];
        float4 v;
        v.x = g.x * (x[j].x - mu) * rs + bb.x;
        v.y = g.y * (x[j].y - mu) * rs + bb.y;
        v.z = g.z * (x[j].z - mu) * rs + bb.z;
        v.w = g.w * (x[j].w - mu) * rs + bb.w;
        o4[j * 64 + lane] = v;
    }
}

// ---------------------------------------------------------------------------
extern "C" void kernel_launch(void* const* d_in, const int* in_sizes, int n_in,
                              void* d_out, int out_size, void* d_ws, size_t ws_size,
                              hipStream_t stream)
{
    const float* queries = (const float*)d_in[0];
    const float* keys    = (const float*)d_in[1];
    const float* Wq      = (const float*)d_in[2];
    const float* bq      = (const float*)d_in[3];
    const float* Wk      = (const float*)d_in[4];
    const float* bk      = (const float*)d_in[5];
    const float* Wv      = (const float*)d_in[6];
    const float* bv      = (const float*)d_in[7];
    const float* gamma   = (const float*)d_in[8];
    const float* beta    = (const float*)d_in[9];
    float* out = (float*)d_out;

    char* ws = (char*)d_ws;
    size_t off = 0;
    auto alloc = [&](size_t bytes) {
        void* p = ws + off;
        off += (bytes + 255) & ~(size_t)255;
        return p;
    };
    u16* qb   = (u16*)alloc((size_t)ROWS * UDIM * 2);
    u16* kb   = (u16*)alloc((size_t)ROWS * UDIM * 2);
    u16* Wqt  = (u16*)alloc((size_t)UDIM * UDIM * 2);
    u16* Wkt  = (u16*)alloc((size_t)UDIM * UDIM * 2);
    u16* Wvt  = (u16*)alloc((size_t)UDIM * UDIM * 2);
    u16* Qp   = (u16*)alloc((size_t)ROWS * UDIM * 2);
    u16* Kp   = (u16*)alloc((size_t)ROWS * UDIM * 2);
    u16* Vtp  = (u16*)alloc((size_t)ROWS * UDIM * 2);
    float* Of = (float*)alloc((size_t)ROWS * UDIM * 4);

    convqk_kernel<<<dim3(ROWS / 4, 2), 256, 0, stream>>>(queries, keys, qb, kb);
    transposeW_kernel<<<dim3(16, 16, 3), 256, 0, stream>>>(Wq, Wk, Wv, Wqt, Wkt, Wvt);
    proj_kernel<<<dim3(64, 4, 3), 256, 0, stream>>>(qb, kb, Wqt, Wkt, Wvt, bq, bk, bv, Qp, Kp, Vtp);
    attn_kernel<<<512, 256, 0, stream>>>(Qp, Kp, Vtp, Of);
    ln_kernel<<<ROWS / 4, 256, 0, stream>>>(Of, queries, gamma, beta, out);
}

// Round 9
// 160.519 us; speedup vs baseline: 1.0599x; 1.0119x over previous
//
#include <hip/hip_runtime.h>
#include <stdint.h>

// Problem constants (B=8, Sq=Sk=1024, D=U=512, H=8, Dh=64)
#define ROWS 8192            // B*Sq = B*Sk
#define UDIM 512
#define SEQ  1024
#define NH   8
#define DH   64
#define SCALE 0.125f         // 1/sqrt(64)
#define LOG2E 1.44269504f
#define SC_Q (SCALE * LOG2E) // folded into Q projection epilogue

typedef unsigned short u16;
typedef __bf16 bf16_t;
typedef bf16_t bf16x8 __attribute__((ext_vector_type(8)));
typedef float f32x4 __attribute__((ext_vector_type(4)));

__device__ __forceinline__ u16 f2bf(float f) {
    union { float f; uint32_t u; } v; v.f = f;
    uint32_t r = v.u + 0x7FFFu + ((v.u >> 16) & 1u);   // round-to-nearest-even
    return (u16)(r >> 16);
}

__device__ __forceinline__ uint32_t pk_bf16(float a, float b) {
#if __has_builtin(__builtin_amdgcn_cvt_pk_bf16_f32)
    typedef __bf16 bf16x2_t __attribute__((ext_vector_type(2)));
    bf16x2_t r = __builtin_amdgcn_cvt_pk_bf16_f32(a, b);
    union { bf16x2_t v; uint32_t u; } c; c.v = r;
    return c.u;
#else
    return (uint32_t)f2bf(a) | ((uint32_t)f2bf(b) << 16);
#endif
}

__device__ __forceinline__ void async_ld16(u16* lds, const u16* g) {
    __builtin_amdgcn_global_load_lds((const __attribute__((address_space(1))) void*)g,
                                     (__attribute__((address_space(3))) void*)lds, 16, 0, 0);
}

// ---------------------------------------------------------------------------
// queries/keys -> bf16 (y selects src); one wave per row
__global__ void convqk_kernel(const float* __restrict__ q, const float* __restrict__ k,
                              u16* __restrict__ qb, u16* __restrict__ kb) {
    int w = threadIdx.x >> 6, lane = threadIdx.x & 63;
    int row = blockIdx.x * 4 + w;
    const float* src = (blockIdx.y == 0) ? q : k;
    u16* dst = (blockIdx.y == 0) ? qb : kb;
    const float4* s4 = (const float4*)(src + (size_t)row * UDIM);
    ushort4* o4 = (ushort4*)(dst + (size_t)row * UDIM);
    for (int j = 0; j < 2; j++) {
        float4 v = s4[j * 64 + lane];
        ushort4 b;
        b.x = f2bf(v.x); b.y = f2bf(v.y); b.z = f2bf(v.z); b.w = f2bf(v.w);
        o4[j * 64 + lane] = b;
    }
}

// W[k][n] (512x512 f32) -> Wt[n][k] bf16, tiled via LDS. blockIdx.z selects q/k/v.
__global__ void transposeW_kernel(const float* __restrict__ Wq, const float* __restrict__ Wk,
                                  const float* __restrict__ Wv, u16* __restrict__ Wqt,
                                  u16* __restrict__ Wkt, u16* __restrict__ Wvt) {
    const float* in = (blockIdx.z == 0) ? Wq : (blockIdx.z == 1) ? Wk : Wv;
    u16* out = (blockIdx.z == 0) ? Wqt : (blockIdx.z == 1) ? Wkt : Wvt;
    __shared__ float tile[32][33];
    int k0 = blockIdx.y * 32, n0 = blockIdx.x * 32;
    int tx = threadIdx.x & 31, ty = threadIdx.x >> 5;
    for (int r = ty; r < 32; r += 8)
        tile[r][tx] = in[(size_t)(k0 + r) * UDIM + n0 + tx];
    __syncthreads();
    for (int r = ty; r < 32; r += 8)
        out[(size_t)(n0 + r) * UDIM + k0 + tx] = f2bf(tile[tx][r]);
}

// ---------------------------------------------------------------------------
// Fused QKV projection, 128x128 tile, XOR-swizzled DOUBLE-BUFFERED staging,
// prefetch at top of each k-iter, ONE barrier per iter (hazards barrier-
// ordered; see round-8 proof). z==0 (Q): epilogue multiplies by SCALE*LOG2E.
// z==2 (V): Vt[b][u][sk].
#define CPAD 136   // c_s row stride in u16
__global__ __launch_bounds__(256, 3) void proj_kernel(
    const u16* __restrict__ qb, const u16* __restrict__ kb,
    const u16* __restrict__ Wqt, const u16* __restrict__ Wkt, const u16* __restrict__ Wvt,
    const float* __restrict__ bq, const float* __restrict__ bk, const float* __restrict__ bv,
    u16* __restrict__ Qp, u16* __restrict__ Kp, u16* __restrict__ Vtp)
{
    const int z = blockIdx.z;
    const u16* A = (z == 0) ? qb : kb;
    const u16* W = (z == 0) ? Wqt : (z == 1) ? Wkt : Wvt;
    const float* bias = (z == 0) ? bq : (z == 1) ? bk : bv;

    __shared__ u16 smem[128 * CPAD];    // staging: a[0]=0, a[1]=4096, b[0]=8192, b[1]=12288
    u16* c_s = smem;

    const int t = threadIdx.x;
    const int lane = t & 63, w = t >> 6;
    const int quad = lane >> 4, l15 = lane & 15;
    const int m0 = blockIdx.x * 128;
    const int n0 = blockIdx.y * 128;

    const int r0 = t >> 2;
    const int s0 = ((t & 3) ^ ((r0 >> 1) & 3)) * 8;
    const u16* Ag0 = &A[(size_t)(m0 + r0) * 512 + s0];
    const u16* Ag1 = Ag0 + (size_t)64 * 512;
    const u16* Wg0 = &W[(size_t)(n0 + r0) * 512 + s0];
    const u16* Wg1 = Wg0 + (size_t)64 * 512;
    u16* al0[2] = { &smem[0 + t * 8],     &smem[4096 + t * 8] };
    u16* al1[2] = { &smem[0 + (t + 256) * 8], &smem[4096 + (t + 256) * 8] };
    u16* bl0[2] = { &smem[8192 + t * 8],      &smem[12288 + t * 8] };
    u16* bl1[2] = { &smem[8192 + (t + 256) * 8], &smem[12288 + (t + 256) * 8] };

    int aoff[2], boff[8];
    for (int mi = 0; mi < 2; mi++) {
        int row = w * 32 + mi * 16 + l15;
        aoff[mi] = row * 32 + (quad ^ ((row >> 1) & 3)) * 8;
    }
    for (int ni = 0; ni < 8; ni++) {
        int row = ni * 16 + l15;
        boff[ni] = row * 32 + (quad ^ ((row >> 1) & 3)) * 8;
    }

    f32x4 acc[2][8];
    for (int mi = 0; mi < 2; mi++)
        for (int ni = 0; ni < 8; ni++)
            acc[mi][ni] = (f32x4){0.f, 0.f, 0.f, 0.f};

    async_ld16(al0[0], Ag0);  async_ld16(al1[0], Ag1);
    async_ld16(bl0[0], Wg0);  async_ld16(bl1[0], Wg1);
    Ag0 += 32; Ag1 += 32; Wg0 += 32; Wg1 += 32;
    __syncthreads();

    for (int kt = 0; kt < 16; kt++) {
        const int cur = kt & 1, nxt = cur ^ 1;
        if (kt < 15) {
            async_ld16(al0[nxt], Ag0);  async_ld16(al1[nxt], Ag1);
            async_ld16(bl0[nxt], Wg0);  async_ld16(bl1[nxt], Wg1);
            Ag0 += 32; Ag1 += 32; Wg0 += 32; Wg1 += 32;
        }
        const int ab = cur ? 4096 : 0, bb = cur ? 12288 : 8192;
        bf16x8 af[2], bf[8];
        for (int mi = 0; mi < 2; mi++) af[mi] = *(const bf16x8*)&smem[ab + aoff[mi]];
        for (int ni = 0; ni < 8; ni++) bf[ni] = *(const bf16x8*)&smem[bb + boff[ni]];
        for (int mi = 0; mi < 2; mi++)
            for (int ni = 0; ni < 8; ni++)
                acc[mi][ni] = __builtin_amdgcn_mfma_f32_16x16x32_bf16(af[mi], bf[ni], acc[mi][ni], 0, 0, 0);
        __syncthreads();
    }

    const float qscale = (z == 0) ? SC_Q : 1.f;
    float bvl[8];
    for (int ni = 0; ni < 8; ni++) bvl[ni] = bias[n0 + ni * 16 + l15];
    for (int mi = 0; mi < 2; mi++)
        for (int ni = 0; ni < 8; ni++)
            for (int r = 0; r < 4; r++)
                acc[mi][ni][r] = fmaxf(acc[mi][ni][r] + bvl[ni], 0.f) * qscale;

    if (z < 2) {
        for (int mi = 0; mi < 2; mi++)
            for (int ni = 0; ni < 8; ni++)
                for (int r = 0; r < 4; r++)
                    c_s[(w * 32 + mi * 16 + quad * 4 + r) * CPAD + ni * 16 + l15] =
                        f2bf(acc[mi][ni][r]);
        __syncthreads();
        u16* outp = (z == 0) ? Qp : Kp;
        for (int j = 0; j < 8; j++) {
            int c = t + j * 256;
            int mrow = c >> 4, col8 = c & 15;
            uint4 d = *(const uint4*)&c_s[mrow * CPAD + col8 * 8];
            *(uint4*)&outp[(size_t)(m0 + mrow) * 512 + n0 + col8 * 8] = d;
        }
    } else {
        for (int mi = 0; mi < 2; mi++)
            for (int ni = 0; ni < 8; ni++) {
                uint2 pk;
                pk.x = pk_bf16(acc[mi][ni][0], acc[mi][ni][1]);
                pk.y = pk_bf16(acc[mi][ni][2], acc[mi][ni][3]);
                *(uint2*)&c_s[(ni * 16 + l15) * CPAD + w * 32 + mi * 16 + quad * 4] = pk;
            }
        __syncthreads();
        const int bb2 = m0 >> 10, sk0 = m0 & 1023;
        for (int j = 0; j < 8; j++) {
            int c = t + j * 256;
            int nrow = c >> 4, col8 = c & 15;
            uint4 d = *(const uint4*)&c_s[nrow * CPAD + col8 * 8];
            *(uint4*)&Vtp[(size_t)(bb2 * 512 + n0 + nrow) * 1024 + sk0 + col8 * 8] = d;
        }
    }
}

// ---------------------------------------------------------------------------
// Flash attention, BQ=64 (grid 1024 -> 4 blocks/CU), double-buffered K/V,
// prefetch at top of iter (hidden under QK^T+exp), TWO barriers per kv-iter
// (round-8 proven ordering):
//   p_s: write(i) < B(i) < read(i) < A'(i) < write(i+1)
//   buf[cur(i)] frag reads < B(i) < prefetch-issue(i+1) into same buffer
//   prefetch(i)->buf[nxt] drained at B(i) < reads at iter i+1
// LDS 40 KB -> 4 blocks/CU; launch_bounds(256,4) for occupancy.
__global__ __launch_bounds__(256, 4) void attn_kernel(
    const u16* __restrict__ Qb, const u16* __restrict__ Kb, const u16* __restrict__ Vt,
    float* __restrict__ O)
{
    __shared__ u16 k_s[2][64 * 64];   // [kv][d] swizzled, double-buffered (16 KB)
    __shared__ u16 v_s[2][64 * 64];   // [d][kv] swizzled, double-buffered (16 KB)
    __shared__ u16 p_s[64 * 64];      // [q][kv] swizzled (8 KB)

    const int t = threadIdx.x, lane = t & 63, w = t >> 6;
    const int quad = lane >> 4, l15 = lane & 15;
    const int fid = blockIdx.x;         // 0..1023
    const int xcd = fid & 7, j = fid >> 3;
    const int hb = xcd * 8 + (j & 7);   // 8 (b,h) groups per XCD
    const int qt = j >> 3;              // 0..15
    const int h = hb & 7, b = hb >> 3;
    const int q0 = qt * 64;

    // ---- staging addresses (pointer-incremented) ----
    const int r0 = t >> 3;                              // 0..31
    const int s0 = ((t & 7) ^ (r0 & 7)) * 8;            // u16 offset
    const u16* kg0 = &Kb[(size_t)(b * 1024 + r0) * 512 + h * 64 + s0];
    const u16* kg1 = kg0 + (size_t)32 * 512;
    const u16* vg0 = &Vt[(size_t)(b * 512 + h * 64 + r0) * 1024 + s0];
    const u16* vg1 = vg0 + (size_t)32 * 1024;
    u16* kd0[2] = { &k_s[0][t * 8], &k_s[1][t * 8] };
    u16* kd1[2] = { &k_s[0][(t + 256) * 8], &k_s[1][(t + 256) * 8] };
    u16* vd0[2] = { &v_s[0][t * 8], &v_s[1][t * 8] };
    u16* vd1[2] = { &v_s[0][(t + 256) * 8], &v_s[1][(t + 256) * 8] };

    // ---- Q B-fragments straight from global (16B/lane contiguous) ----
    const int prow = w * 16 + l15;
    bf16x8 bqf[2];
    {
        int qrow = b * 1024 + q0 + prow;
        for (int kk = 0; kk < 2; kk++)
            bqf[kk] = *(const bf16x8*)&Qb[(size_t)qrow * 512 + h * 64 + kk * 32 + quad * 8];
    }

    // ---- hoisted LDS fragment offsets ----
    int koff[4][2], pwoff[4], proff[2];
    for (int mi = 0; mi < 4; mi++) {
        int row = mi * 16 + l15;
        koff[mi][0] = row * 64 + (quad ^ (row & 7)) * 8;
        koff[mi][1] = row * 64 + ((4 + quad) ^ (row & 7)) * 8;
    }
    for (int mi = 0; mi < 4; mi++)
        pwoff[mi] = prow * 64 + ((mi * 2 + (quad >> 1)) ^ (prow & 7)) * 8 + (quad & 1) * 4;
    for (int kk = 0; kk < 2; kk++)
        proff[kk] = prow * 64 + ((kk * 4 + quad) ^ (prow & 7)) * 8;

    float l_lane = 0.f;
    f32x4 o_acc[4];
    for (int mi = 0; mi < 4; mi++) o_acc[mi] = (f32x4){0.f, 0.f, 0.f, 0.f};

    // prologue: stage buf 0
    async_ld16(kd0[0], kg0);  async_ld16(kd1[0], kg1);
    async_ld16(vd0[0], vg0);  async_ld16(vd1[0], vg1);
    kg0 += (size_t)64 * 512; kg1 += (size_t)64 * 512;
    vg0 += 64; vg1 += 64;
    __syncthreads();

    for (int it = 0; it < 16; it++) {
        const int cur = it & 1, nxt = cur ^ 1;

        // prefetch next kv-tile (hidden under phase 1; drained at barrier B)
        if (it < 15) {
            async_ld16(kd0[nxt], kg0);  async_ld16(kd1[nxt], kg1);
            async_ld16(vd0[nxt], vg0);  async_ld16(vd1[nxt], vg1);
            kg0 += (size_t)64 * 512; kg1 += (size_t)64 * 512;
            vg0 += 64; vg1 += 64;
        }

        // phase 1: K/V fragment reads from cur buffer
        bf16x8 ak[4][2];
        for (int mi = 0; mi < 4; mi++) {
            ak[mi][0] = *(const bf16x8*)&k_s[cur][koff[mi][0]];
            ak[mi][1] = *(const bf16x8*)&k_s[cur][koff[mi][1]];
        }
        bf16x8 av[2][4];
        for (int kk = 0; kk < 2; kk++)
            for (int mi = 0; mi < 4; mi++)
                av[kk][mi] = *(const bf16x8*)&v_s[cur][koff[mi][kk]];  // same row formula (d rows)

        // S^T = K·Q^T (log2-scaled via Q), exp2, pack, P -> p_s
        f32x4 st[4];
        for (int mi = 0; mi < 4; mi++) {
            f32x4 a = (f32x4){0.f, 0.f, 0.f, 0.f};
            a = __builtin_amdgcn_mfma_f32_16x16x32_bf16(ak[mi][0], bqf[0], a, 0, 0, 0);
            a = __builtin_amdgcn_mfma_f32_16x16x32_bf16(ak[mi][1], bqf[1], a, 0, 0, 0);
            st[mi] = a;
        }
        for (int mi = 0; mi < 4; mi++) {
            float p0 = exp2f(st[mi][0]);
            float p1 = exp2f(st[mi][1]);
            float p2 = exp2f(st[mi][2]);
            float p3 = exp2f(st[mi][3]);
            l_lane += (p0 + p1) + (p2 + p3);
            uint2 pk;
            pk.x = pk_bf16(p0, p1);
            pk.y = pk_bf16(p2, p3);
            *(uint2*)&p_s[pwoff[mi]] = pk;
        }

        __syncthreads();   // barrier B: P visible, prefetch drained, frag reads done

        // phase 2: O^T += V^T · P (reads p_s + registers only)
        for (int kk = 0; kk < 2; kk++) {
            bf16x8 bp = *(const bf16x8*)&p_s[proff[kk]];
            for (int mi = 0; mi < 4; mi++)
                o_acc[mi] = __builtin_amdgcn_mfma_f32_16x16x32_bf16(av[kk][mi], bp, o_acc[mi], 0, 0, 0);
        }

        if (it < 15)
            __syncthreads();   // barrier A': p_s reads done before next iter's writes
    }

    float l = l_lane;
    l += __shfl_xor(l, 16, 64);
    l += __shfl_xor(l, 32, 64);
    float inv = 1.f / l;
    int gq = q0 + prow;
    for (int mi = 0; mi < 4; mi++) {
        float4 o;
        o.x = o_acc[mi][0] * inv;
        o.y = o_acc[mi][1] * inv;
        o.z = o_acc[mi][2] * inv;
        o.w = o_acc[mi][3] * inv;
        *(float4*)&O[(size_t)(b * 1024 + gq) * 512 + h * 64 + mi * 16 + quad * 4] = o;
    }
}

// ---------------------------------------------------------------------------
// LayerNorm epilogue with inline qmask: mask = (sum|q_row| > 0);
// x = O*mask + q; LN over U=512; one wave per row.
__global__ void ln_kernel(const float* __restrict__ O, const float* __restrict__ q,
                          const float* __restrict__ gamma, const float* __restrict__ beta,
                          float* __restrict__ out)
{
    int w = threadIdx.x >> 6, lane = threadIdx.x & 63;
    int row = blockIdx.x * 4 + w;
    const float4* O4 = (const float4*)(O + (size_t)row * UDIM);
    const float4* q4 = (const float4*)(q + (size_t)row * UDIM);
    float4* o4 = (float4*)(out + (size_t)row * UDIM);

    float4 qq[2], oo[2];
    float am = 0.f;
    for (int j = 0; j < 2; j++) {
        qq[j] = q4[j * 64 + lane];
        oo[j] = O4[j * 64 + lane];
        am += fabsf(qq[j].x) + fabsf(qq[j].y) + fabsf(qq[j].z) + fabsf(qq[j].w);
    }
    for (int off = 32; off; off >>= 1) am += __shfl_xor(am, off, 64);
    float mask = (am > 0.f) ? 1.f : 0.f;

    float4 x[2];
    float s = 0.f, ss = 0.f;
    for (int j = 0; j < 2; j++) {
        float4 v;
        v.x = oo[j].x * mask + qq[j].x;
        v.y = oo[j].y * mask + qq[j].y;
        v.z = oo[j].z * mask + qq[j].z;
        v.w = oo[j].w * mask + qq[j].w;
        x[j] = v;
        s += v.x + v.y + v.z + v.w;
        ss += v.x * v.x + v.y * v.y + v.z * v.z + v.w * v.w;
    }
    for (int off = 32; off; off >>= 1) {
        s += __shfl_xor(s, off, 64);
        ss += __shfl_xor(ss, off, 64);
    }
    float mu = s * (1.f / 512.f);
    float var = ss * (1.f / 512.f) - mu * mu;
    float rs = rsqrtf(var + 1e-8f);
    for (int j = 0; j < 2; j++) {
        float4 g = ((const float4*)gamma)[j * 64 + lane];
        float4 bb = ((const float4*)beta)[j * 64 + lane];
        float4 v;
        v.x = g.x * (x[j].x - mu) * rs + bb.x;
        v.y = g.y * (x[j].y - mu) * rs + bb.y;
        v.z = g.z * (x[j].z - mu) * rs + bb.z;
        v.w = g.w * (x[j].w - mu) * rs + bb.w;
        o4[j * 64 + lane] = v;
    }
}

// ---------------------------------------------------------------------------
extern "C" void kernel_launch(void* const* d_in, const int* in_sizes, int n_in,
                              void* d_out, int out_size, void* d_ws, size_t ws_size,
                              hipStream_t stream)
{
    const float* queries = (const float*)d_in[0];
    const float* keys    = (const float*)d_in[1];
    const float* Wq      = (const float*)d_in[2];
    const float* bq      = (const float*)d_in[3];
    const float* Wk      = (const float*)d_in[4];
    const float* bk      = (const float*)d_in[5];
    const float* Wv      = (const float*)d_in[6];
    const float* bv      = (const float*)d_in[7];
    const float* gamma   = (const float*)d_in[8];
    const float* beta    = (const float*)d_in[9];
    float* out = (float*)d_out;

    char* ws = (char*)d_ws;
    size_t off = 0;
    auto alloc = [&](size_t bytes) {
        void* p = ws + off;
        off += (bytes + 255) & ~(size_t)255;
        return p;
    };
    u16* qb   = (u16*)alloc((size_t)ROWS * UDIM * 2);
    u16* kb   = (u16*)alloc((size_t)ROWS * UDIM * 2);
    u16* Wqt  = (u16*)alloc((size_t)UDIM * UDIM * 2);
    u16* Wkt  = (u16*)alloc((size_t)UDIM * UDIM * 2);
    u16* Wvt  = (u16*)alloc((size_t)UDIM * UDIM * 2);
    u16* Qp   = (u16*)alloc((size_t)ROWS * UDIM * 2);
    u16* Kp   = (u16*)alloc((size_t)ROWS * UDIM * 2);
    u16* Vtp  = (u16*)alloc((size_t)ROWS * UDIM * 2);
    float* Of = (float*)alloc((size_t)ROWS * UDIM * 4);

    convqk_kernel<<<dim3(ROWS / 4, 2), 256, 0, stream>>>(queries, keys, qb, kb);
    transposeW_kernel<<<dim3(16, 16, 3), 256, 0, stream>>>(Wq, Wk, Wv, Wqt, Wkt, Wvt);
    proj_kernel<<<dim3(64, 4, 3), 256, 0, stream>>>(qb, kb, Wqt, Wkt, Wvt, bq, bk, bv, Qp, Kp, Vtp);
    attn_kernel<<<1024, 256, 0, stream>>>(Qp, Kp, Vtp, Of);
    ln_kernel<<<ROWS / 4, 256, 0, stream>>>(Of, queries, gamma, beta, out);
}